// Round 2
// baseline (654.703 us; speedup 1.0000x reference)
//
#include <hip/hip_runtime.h>
#include <hip/hip_bf16.h>

// Problem dims
// B=4, T=4096 -> BT=16384 tokens; D=4096; G=1, C=4, K=128, I=4 (I2=2), M=32
// Fused GEMM: [16384 x 4096] x [4096 x 640]  (640 = 512 hidden + 128 dd)

typedef _Float16 half8 __attribute__((ext_vector_type(8)));
typedef float f32x4 __attribute__((ext_vector_type(4)));

#define BT_TOK 16384
#define DDIM   4096

// output offsets (floats) in return order
static constexpr int OFF_PRE_QW1  = 0;
static constexpr int OFF_PRE_QW2  = 1048576;
static constexpr int OFF_PRE_KW1  = 2097152;
static constexpr int OFF_PRE_KW2  = 3145728;
static constexpr int OFF_PRE_QDD  = 4194304;
static constexpr int OFF_PRE_KDD  = 4718592;
static constexpr int OFF_POST_QW1 = 5242880;
static constexpr int OFF_POST_QW2 = 6291456;
static constexpr int OFF_POST_KW1 = 7340032;
static constexpr int OFF_POST_KW2 = 8388608;
static constexpr int OFF_POST_QDD = 9437184;
static constexpr int OFF_POST_KDD = 9961472;
static constexpr int OFF_KW       = 10485760;

typedef __attribute__((address_space(3))) void lds_void;
typedef const __attribute__((address_space(1))) void gbl_void;

__device__ __forceinline__ void gload16(const void* g, void* l) {
  // async global->LDS, 16B per lane; LDS dest is wave-uniform base + lane*16
  __builtin_amdgcn_global_load_lds((gbl_void*)g, (lds_void*)l, 16, 0, 0);
}

// ---------------------------------------------------------------------------
// Kernel 1a: query_vec f32 -> fp16 (A matrix), vectorized 8 elems/thread/iter
__global__ __launch_bounds__(256) void convert_a(const float* __restrict__ q,
                                                 _Float16* __restrict__ a) {
  const int stride = gridDim.x * blockDim.x;
  for (int i = blockIdx.x * blockDim.x + threadIdx.x; i < (BT_TOK * DDIM) / 8;
       i += stride) {
    const float4* p = (const float4*)(q + (size_t)i * 8);
    float4 x = p[0], y = p[1];
    half8 h;
    h[0] = (_Float16)x.x; h[1] = (_Float16)x.y;
    h[2] = (_Float16)x.z; h[3] = (_Float16)x.w;
    h[4] = (_Float16)y.x; h[5] = (_Float16)y.y;
    h[6] = (_Float16)y.z; h[7] = (_Float16)y.w;
    *(half8*)(a + (size_t)i * 8) = h;
  }
}

// ---------------------------------------------------------------------------
// Kernel 1b: build B^T fp16 [640][4096] from dw1 [4096][512] and dd_w [4096][128]
__global__ __launch_bounds__(256) void build_bt(const float* __restrict__ dw1,
                                                const float* __restrict__ ddw,
                                                _Float16* __restrict__ Bt) {
  __shared__ float tile[64][65];
  const int bn = blockIdx.x % 10, bd = blockIdx.x / 10;
  const int n0 = bn * 64, d0 = bd * 64;
  const int tid = threadIdx.x;
  const int ln = tid & 63;  // lane along contiguous dim
  const int rr = tid >> 6;  // 0..3
#pragma unroll
  for (int i = 0; i < 16; ++i) {
    int dl = rr + i * 4;  // 0..63
    int d = d0 + dl, n = n0 + ln;
    float v = (n < 512) ? dw1[d * 512 + n] : ddw[d * 128 + (n - 512)];
    tile[dl][ln] = v;
  }
  __syncthreads();
#pragma unroll
  for (int i = 0; i < 16; ++i) {
    int nl = rr + i * 4;
    Bt[(size_t)(n0 + nl) * DDIM + d0 + ln] = (_Float16)tile[ln][nl];
  }
}

// ---------------------------------------------------------------------------
// Kernel 1c: qkwT[c][n][k] fp16 from qkw flat [c][k][n] (n = i*32+m)
__global__ __launch_bounds__(256) void build_qkwT(const float* __restrict__ qkw,
                                                  _Float16* __restrict__ qT) {
  const int c = blockIdx.x;
  for (int e = threadIdx.x; e < 16384; e += 256) {
    int n = e >> 7, k = e & 127;
    qT[c * 16384 + n * 128 + k] = (_Float16)qkw[c * 16384 + k * 128 + n];
  }
}

// ---------------------------------------------------------------------------
// Kernel 2: main GEMM 16384x4096x640 fp16 MFMA, 128x128 tile, BK=64.
// A [16384][4096] fp16, Bt [640][4096] fp16.
// Epilogue: cols<512 -> gelu(exact) -> Hg fp16 [16384][512]
//           cols>=512 -> tanh -> dd outputs (f32) directly to d_out.
__global__ __launch_bounds__(256) void gemm_main(const _Float16* __restrict__ A,
                                                 const _Float16* __restrict__ Bt,
                                                 _Float16* __restrict__ Hg,
                                                 float* __restrict__ out) {
  __shared__ _Float16 As[8192];  // [128 rows][8 kslots of 8 halfs], XOR-swizzled
  __shared__ _Float16 Bs[8192];

  // XCD-bijective swizzle (grid 640 = 8*80)
  int wg = (int)blockIdx.x;
  wg = (wg & 7) * 80 + (wg >> 3);
  const int mtile = wg / 5, ntile = wg - mtile * 5;
  const int m0 = mtile << 7, n0 = ntile << 7;

  const int tid = threadIdx.x;
  const int wave = tid >> 6, lane = tid & 63;
  const int lq = lane >> 4, lc = lane & 15;

  // staging: 1024 16B-slots per tile; slot s -> row=s>>3, kslot=s&7.
  // LDS written LINEARLY (gload_lds rule); global source pre-swizzled:
  // gslot = (s&7) ^ (row&7); read back with kslot = kb ^ (row&7).  [rule #21]
  int aoff[4], boff[4];
  _Float16* lA[4];
  _Float16* lB[4];
#pragma unroll
  for (int j = 0; j < 4; ++j) {
    int slot = j * 256 + wave * 64 + lane;
    int row = slot >> 3;
    int gs = (slot & 7) ^ (row & 7);
    aoff[j] = (m0 + row) * DDIM + gs * 8;
    boff[j] = (n0 + row) * DDIM + gs * 8;
    lA[j] = As + j * 2048 + wave * 512;  // wave-uniform LDS base
    lB[j] = Bs + j * 2048 + wave * 512;
  }
  const int wm = (wave >> 1) << 6, wn = (wave & 1) << 6;

  f32x4 acc[4][4];
#pragma unroll
  for (int i = 0; i < 4; ++i)
#pragma unroll
    for (int j = 0; j < 4; ++j) acc[i][j] = f32x4{0.f, 0.f, 0.f, 0.f};

  for (int k0 = 0; k0 < DDIM; k0 += 64) {
#pragma unroll
    for (int j = 0; j < 4; ++j) gload16(A + aoff[j] + k0, lA[j]);
#pragma unroll
    for (int j = 0; j < 4; ++j) gload16(Bt + boff[j] + k0, lB[j]);
    __syncthreads();  // compiler emits vmcnt(0) drain -> LDS tiles ready
#pragma unroll
    for (int kk = 0; kk < 2; ++kk) {
      half8 af[4], bf[4];
      const int kb = kk * 4 + lq;  // desired k-chunk
#pragma unroll
      for (int f = 0; f < 4; ++f) {
        int rowA = wm + f * 16 + lc;
        af[f] = *(const half8*)(As + rowA * 64 + ((kb ^ (rowA & 7)) << 3));
        int rowB = wn + f * 16 + lc;
        bf[f] = *(const half8*)(Bs + rowB * 64 + ((kb ^ (rowB & 7)) << 3));
      }
#pragma unroll
      for (int mf = 0; mf < 4; ++mf)
#pragma unroll
        for (int nf = 0; nf < 4; ++nf)
          acc[mf][nf] = __builtin_amdgcn_mfma_f32_16x16x32_f16(
              af[mf], bf[nf], acc[mf][nf], 0, 0, 0);
    }
    __syncthreads();
  }

  // Epilogue. C/D frag: col = lane&15, row = (lane>>4)*4 + reg  [m89]
  if (ntile < 4) {
#pragma unroll
    for (int mf = 0; mf < 4; ++mf)
#pragma unroll
      for (int nf = 0; nf < 4; ++nf)
#pragma unroll
        for (int r = 0; r < 4; ++r) {
          int row = m0 + wm + mf * 16 + lq * 4 + r;
          int col = n0 + wn + nf * 16 + lc;
          float v = acc[mf][nf][r];
          float g = 0.5f * v * (1.0f + erff(v * 0.70710678118654752f));
          Hg[(size_t)row * 512 + col] = (_Float16)g;
        }
  } else {
#pragma unroll
    for (int mf = 0; mf < 4; ++mf)
#pragma unroll
      for (int nf = 0; nf < 4; ++nf)
#pragma unroll
        for (int r = 0; r < 4; ++r) {
          int row = m0 + wm + mf * 16 + lq * 4 + r;
          int j = wn + nf * 16 + lc;  // 0..127
          int t = j >> 5;             // 0:pre_qdd 1:pre_kdd 2:post_qdd 3:post_kdd
          int base = (t & 2) ? ((t & 1) ? OFF_POST_KDD : OFF_POST_QDD)
                             : ((t & 1) ? OFF_PRE_KDD : OFF_PRE_QDD);
          out[base + row * 32 + (j & 31)] = tanhf(acc[mf][nf][r]);
        }
  }
}

// ---------------------------------------------------------------------------
// Kernel 3: per-token epilogue. 16 tokens/block, wave w owns c-slot w.
// w[c,i,m] = sum_k h[c*128+k]*qkw[c,k,i,m] via MFMA (M=16 tokens, N=128, K=128)
// then rmsnorm(w1), writes, then cooperative KW outer products (coalesced).
__global__ __launch_bounds__(256) void epilogue_k(const _Float16* __restrict__ Hg,
                                                  const _Float16* __restrict__ qT,
                                                  float* __restrict__ out) {
  __shared__ float stash[2][4][16][32];  // [pre/post][i][tok][m]  (c=1,3 waves)
  __shared__ float ddl[2][16][32];       // [pre/post][tok][m] kdd
  const int tid = threadIdx.x;
  const int wave = tid >> 6, lane = tid & 63;
  const int lq = lane >> 4, lc = lane & 15;
  const int tok0 = blockIdx.x * 16;
  const int c = wave;  // 0:pre_q 1:pre_k 2:post_q 3:post_k

  // cooperative kdd preload (written by gemm_main)
#pragma unroll
  for (int z = 0; z < 4; ++z) {
    int idx = z * 256 + tid;  // 0..1023
    int pp = idx >> 9, tl = (idx >> 5) & 15, m = idx & 31;
    ddl[pp][tl][m] =
        out[(pp ? OFF_POST_KDD : OFF_PRE_KDD) + (tok0 + tl) * 32 + m];
  }

  // A-frag: row = token (lc), k = lq*8+e within each 32-chunk
  const _Float16* arow = Hg + (size_t)(tok0 + lc) * 512 + c * 128 + lq * 8;
  half8 af[4];
#pragma unroll
  for (int kf = 0; kf < 4; ++kf) af[kf] = *(const half8*)(arow + kf * 32);

  f32x4 acc[8];
#pragma unroll
  for (int nf = 0; nf < 8; ++nf) acc[nf] = f32x4{0.f, 0.f, 0.f, 0.f};
#pragma unroll
  for (int nf = 0; nf < 8; ++nf) {
    const _Float16* brow = qT + c * 16384 + (nf * 16 + lc) * 128 + lq * 8;
#pragma unroll
    for (int kf = 0; kf < 4; ++kf) {
      half8 bf = *(const half8*)(brow + kf * 32);
      acc[nf] = __builtin_amdgcn_mfma_f32_16x16x32_f16(af[kf], bf, acc[nf], 0, 0, 0);
    }
  }

  // output bases, computed arithmetically (no runtime-indexed arrays, rule #20)
  const int w1base = (c >> 1) * OFF_POST_QW1 + (c & 1) * OFF_PRE_KW1;
  const int w2base = w1base + OFF_PRE_QW2;
  const int cs = c >> 1;
  const bool isk = (c & 1);

  // acc[nf][r]: token = tok0 + lq*4 + r, n = nf*16 + lc; n = i*32 + m
#pragma unroll
  for (int i = 0; i < 4; ++i) {
    float vn0[4], vn1[4];
#pragma unroll
    for (int r = 0; r < 4; ++r) {
      vn0[r] = acc[2 * i][r];      // m = lc
      vn1[r] = acc[2 * i + 1][r];  // m = 16 + lc
    }
    if (i < 2) {  // rmsnorm over the 32 m-values (16 lanes x 2 regs)
#pragma unroll
      for (int r = 0; r < 4; ++r) {
        float ss = vn0[r] * vn0[r] + vn1[r] * vn1[r];
        ss += __shfl_xor(ss, 1);
        ss += __shfl_xor(ss, 2);
        ss += __shfl_xor(ss, 4);
        ss += __shfl_xor(ss, 8);
        float sc = rsqrtf(ss * 0.03125f + 1e-6f);
        vn0[r] *= sc;
        vn1[r] *= sc;
      }
    }
    const int basei = ((i < 2) ? w1base : w2base) + (i & 1) * 32;
#pragma unroll
    for (int r = 0; r < 4; ++r) {
      int token = tok0 + lq * 4 + r;
      out[basei + token * 64 + lc] = vn0[r];
      out[basei + token * 64 + 16 + lc] = vn1[r];
      if (isk) {
        stash[cs][i][lq * 4 + r][lc] = vn0[r];
        stash[cs][i][lq * 4 + r][16 + lc] = vn1[r];
      }
    }
  }
  __syncthreads();

  // KW[pp][tl][m][n] = sum_{i<2} w1n[i][m]*w2[i][n] + kdd[m]*delta(m,n)
  // 32768 elems / 256 threads; consecutive tid -> consecutive addr (coalesced)
#pragma unroll 8
  for (int it = 0; it < 128; ++it) {
    int flat = it * 256 + tid;
    int pp = flat >> 14, rest = flat & 16383;
    int tl = rest >> 10, mrow = (rest >> 5) & 31, n = rest & 31;
    float v = stash[pp][0][tl][mrow] * stash[pp][2][tl][n] +
              stash[pp][1][tl][mrow] * stash[pp][3][tl][n];
    if (mrow == n) v += ddl[pp][tl][n];
    out[OFF_KW + (tok0 + tl) * 2048 + pp * 1024 + mrow * 32 + n] = v;
  }
}

// ---------------------------------------------------------------------------
extern "C" void kernel_launch(void* const* d_in, const int* in_sizes, int n_in,
                              void* d_out, int out_size, void* d_ws, size_t ws_size,
                              hipStream_t stream) {
  const float* q   = (const float*)d_in[0];  // [4,4096,4096]
  const float* dw1 = (const float*)d_in[1];  // [4096,1,4,128]
  const float* qkw = (const float*)d_in[2];  // [1,4,128,4,32]
  const float* ddw = (const float*)d_in[3];  // [4096,1,128]
  float* out = (float*)d_out;

  _Float16* Ah = (_Float16*)d_ws;                    // 16384*4096   (128 MiB)
  _Float16* Bt = Ah + (size_t)BT_TOK * DDIM;         // 640*4096     (5 MiB)
  _Float16* Hg = Bt + (size_t)640 * DDIM;            // 16384*512    (16 MiB)
  _Float16* qT = Hg + (size_t)BT_TOK * 512;          // 4*128*128    (128 KiB)

  convert_a<<<2048, 256, 0, stream>>>(q, Ah);
  build_bt<<<640, 256, 0, stream>>>(dw1, ddw, Bt);
  build_qkwT<<<4, 256, 0, stream>>>(qkw, qT);
  gemm_main<<<640, 256, 0, stream>>>(Ah, Bt, Hg, out);
  epilogue_k<<<1024, 256, 0, stream>>>(Hg, qT, out);
}